// Round 11
// baseline (327.772 us; speedup 1.0000x reference)
//
#include <hip/hip_runtime.h>
#include <math.h>

#define N_NODES 50000
#define N_EDGES 800000
#define IN_CH   256
#define OUT_CH  64
#define HEADS   4
#define NEG_SLOPE 0.2f
#define NCOLS   320           // W (256) || W_res (64)
#define NTILES  20            // NCOLS / 16
#define NKK     8             // IN_CH / 32
#define PACK_BLOCKS 40        // NKK*NTILES*64 / 256
#define GEMM_BLOCKS 782       // (N_NODES+63)/64
#define NBINS   782           // 64-dst bins (bin = dst>>6); 782*64 = 50048
#define P1_BLOCKS 256         // edge-partition blocks
#define EPB     3125          // edges per partition block = N_EDGES/256
#define AGG_BLOCKS 12500      // N_NODES/4, single dispatch (R8: 64.7us)
#define STASH_CAP 1280        // max edges per 64-dst bin (mean 1023, sd 32)
// R11: gemm chunked across the four lean CSR-stage dispatches (R9 failed
// because stages were BLOATED to 1024 blocks; R10's lean shapes kept here
// byte-identical). Fusion of independent halves measured max() not sum()
// (R0-R6, R10).
#define GA 200
#define GB 100
#define GC 300
#define GD 182                // GA+GB+GC+GD = 782

typedef __attribute__((ext_vector_type(8))) short short8;
typedef __attribute__((ext_vector_type(4))) float f32x4;

__device__ __forceinline__ float lrelu(float v) {
    return v > 0.f ? v : NEG_SLOPE * v;
}
__device__ __forceinline__ unsigned bf16_rne(float f) {
    unsigned u = __float_as_uint(f);
    return (u + 0x7FFFu + ((u >> 16) & 1u)) >> 16;
}
__device__ __forceinline__ unsigned pack2(float lo, float hi) {
    return bf16_rne(lo) | (bf16_rne(hi) << 16);
}
__device__ __forceinline__ float bflo(unsigned u) { return __uint_as_float(u << 16); }
__device__ __forceinline__ float bfhi(unsigned u) { return __uint_as_float(u & 0xFFFF0000u); }
__device__ __forceinline__ short8 as_short8(uint4 u) {
    union { uint4 u4; short8 s8; } cv; cv.u4 = u; return cv.s8;
}

// ---------------------------------------------------------------------------
// pack_B: [W | W_res] fp32 -> bf16 MFMA B-fragment order (tiny, 40 blocks).
// Must complete before any gemm chunk (Bp dependency) -> own dispatch.
// ---------------------------------------------------------------------------
__global__ __launch_bounds__(256) void pack_B(
    const float* __restrict__ W, const float* __restrict__ Wres,
    uint4* __restrict__ Bp)
{
    const int idx  = blockIdx.x * 256 + threadIdx.x;   // 0..10239
    const int kk   = idx / (NTILES * 64);
    const int rem  = idx - kk * (NTILES * 64);
    const int t    = rem >> 6;
    const int lane = rem & 63;
    const int colL = lane & 15, quad = lane >> 4;
    const int col  = t * 16 + colL;
    const int k0   = kk * 32 + quad * 8;
    float v[8];
    #pragma unroll
    for (int j = 0; j < 8; ++j) {
        const int k = k0 + j;
        v[j] = (col < IN_CH) ? W[(size_t)k * IN_CH + col]
                             : Wres[(size_t)k * OUT_CH + (col - IN_CH)];
    }
    uint4 u;
    u.x = pack2(v[0], v[1]); u.y = pack2(v[2], v[3]);
    u.z = pack2(v[4], v[5]); u.w = pack2(v[6], v[7]);
    Bp[(kk * NTILES + t) * 64 + lane] = u;
}

// ---------------------------------------------------------------------------
// gemm_body: R6/R10's proven 64-row/256-thr MFMA transform + fused logits.
// Wave wv owns col-tiles {wv,4+wv,8+wv,12+wv,16+wv} over 4 row-groups.
// ---------------------------------------------------------------------------
__device__ __forceinline__ void gemm_body(
    const int n0, const float* __restrict__ x, const uint4* __restrict__ Bp,
    uint2* __restrict__ xw2, float* __restrict__ xres,
    const float* __restrict__ attS, const float* __restrict__ attD,
    float* __restrict__ asrc, float* __restrict__ adst,
    uint4* Alds, float (*logS)[HEADS], float (*logD)[HEADS])
{
    const int tid = threadIdx.x;

    logS[tid >> 2][tid & 3] = 0.f;
    logD[tid >> 2][tid & 3] = 0.f;

    #pragma unroll
    for (int i = 0; i < 8; ++i) {
        const int e    = i * 256 + tid;
        const int g    = e >> 9;
        const int kk   = (e >> 6) & 7;
        const int lane = e & 63;
        const int cL   = lane & 15, qd = lane >> 4;
        const int row  = n0 + g * 16 + cL;
        const int k0   = kk * 32 + qd * 8;
        uint4 u = make_uint4(0u, 0u, 0u, 0u);
        if (row < N_NODES) {
            const float4 a = *reinterpret_cast<const float4*>(x + (size_t)row * IN_CH + k0);
            const float4 b = *reinterpret_cast<const float4*>(x + (size_t)row * IN_CH + k0 + 4);
            u.x = pack2(a.x, a.y); u.y = pack2(a.z, a.w);
            u.z = pack2(b.x, b.y); u.w = pack2(b.z, b.w);
        }
        Alds[(g * NKK + kk) * 64 + lane] = u;
    }
    __syncthreads();

    const int lane = tid & 63;
    const int wv   = tid >> 6;
    const int colL = lane & 15, quad = lane >> 4;

    f32x4 acc[4][5];
    #pragma unroll
    for (int rg = 0; rg < 4; ++rg)
        #pragma unroll
        for (int j = 0; j < 5; ++j) acc[rg][j] = (f32x4){0.f, 0.f, 0.f, 0.f};

    for (int kk = 0; kk < NKK; ++kk) {
        uint4 bu[5];
        #pragma unroll
        for (int j = 0; j < 5; ++j)
            bu[j] = Bp[(kk * NTILES + j * 4 + wv) * 64 + lane];
        #pragma unroll
        for (int rg = 0; rg < 4; ++rg) {
            const short8 a = as_short8(Alds[(rg * NKK + kk) * 64 + lane]);
            #pragma unroll
            for (int j = 0; j < 5; ++j)
                acc[rg][j] = __builtin_amdgcn_mfma_f32_16x16x32_bf16(
                    a, as_short8(bu[j]), acc[rg][j], 0, 0, 0);
        }
    }

    #pragma unroll
    for (int rg = 0; rg < 4; ++rg) {
        #pragma unroll
        for (int r = 0; r < 4; ++r) {
            const int row = n0 + rg * 16 + quad * 4 + r;
            if (row < N_NODES) {
                xw2[(size_t)row * 64 + wv * 16 + colL] = make_uint2(
                    pack2(acc[rg][0][r], acc[rg][1][r]),
                    pack2(acc[rg][2][r], acc[rg][3][r]));
                xres[(size_t)row * OUT_CH + wv * 16 + colL] = acc[rg][4][r];
            }
        }
    }

    float aSr[HEADS], aDr[HEADS];
    #pragma unroll
    for (int h = 0; h < HEADS; ++h) {
        aSr[h] = attS[h * 64 + wv * 16 + colL];
        aDr[h] = attD[h * 64 + wv * 16 + colL];
    }
    #pragma unroll
    for (int rg = 0; rg < 4; ++rg) {
        #pragma unroll
        for (int h = 0; h < HEADS; ++h) {
            #pragma unroll
            for (int r = 0; r < 4; ++r) {
                float vS = acc[rg][h][r] * aSr[h];
                float vD = acc[rg][h][r] * aDr[h];
                #pragma unroll
                for (int m = 1; m < 16; m <<= 1) {      // stays within quad
                    vS += __shfl_xor(vS, m);
                    vD += __shfl_xor(vD, m);
                }
                if (colL == 0) {
                    atomicAdd(&logS[rg * 16 + quad * 4 + r][h], vS);
                    atomicAdd(&logD[rg * 16 + quad * 4 + r][h], vD);
                }
            }
        }
    }
    __syncthreads();
    {
        const int rl = tid >> 2, h = tid & 3;
        const int row = n0 + rl;
        if (row < N_NODES) {
            asrc[(size_t)row * HEADS + h] = logS[rl][h];
            adst[(size_t)row * HEADS + h] = logD[rl][h];
        }
    }
}

// ---------------------------------------------------------------------------
// D1: blocks [0,256) histogram (lean R10 shape); [256,+GA) gemm chunk A.
// ---------------------------------------------------------------------------
__global__ __launch_bounds__(256) void k1_hist_gemm(
    const float* __restrict__ x, const uint4* __restrict__ Bp,
    uint2* __restrict__ xw2, float* __restrict__ xres,
    const int* __restrict__ ei, int* __restrict__ M,
    const float* __restrict__ attS, const float* __restrict__ attD,
    float* __restrict__ asrc, float* __restrict__ adst)
{
    __shared__ uint4 Alds[4 * NKK * 64];   // 32 KB
    __shared__ float logS[64][HEADS];
    __shared__ float logD[64][HEADS];

    if (blockIdx.x < P1_BLOCKS) {
        const int blk = blockIdx.x;
        int* lh = (int*)Alds;              // 3.1 KB
        for (int b = threadIdx.x; b < NBINS; b += 256) lh[b] = 0;
        __syncthreads();
        const int e0 = blk * EPB;
        #pragma unroll
        for (int r = 0; r < 13; ++r) {
            const int idx = (r << 8) + threadIdx.x;
            if (idx < EPB)
                atomicAdd(&lh[ei[N_EDGES + e0 + idx] >> 6], 1);
        }
        __syncthreads();
        for (int b = threadIdx.x; b < NBINS; b += 256)
            M[(size_t)b * P1_BLOCKS + blk] = lh[b];
        return;
    }
    gemm_body((blockIdx.x - P1_BLOCKS) * 64,
              x, Bp, xw2, xres, attS, attD, asrc, adst, Alds, logS, logD);
}

// ---------------------------------------------------------------------------
// D2: blocks [0,782) binscan_M (lean); [782,+GB) gemm chunk B.
// ---------------------------------------------------------------------------
__global__ __launch_bounds__(256) void k2_scan_gemm(
    const float* __restrict__ x, const uint4* __restrict__ Bp,
    uint2* __restrict__ xw2, float* __restrict__ xres,
    const float* __restrict__ attS, const float* __restrict__ attD,
    float* __restrict__ asrc, float* __restrict__ adst,
    int* __restrict__ M, int* __restrict__ binCnt)
{
    __shared__ uint4 Alds[4 * NKK * 64];
    __shared__ float logS[64][HEADS];
    __shared__ float logD[64][HEADS];
    const int t = threadIdx.x, lane = t & 63, w = t >> 6;

    if (blockIdx.x < NBINS) {
        int* ws = (int*)Alds;
        const int b = blockIdx.x;
        const int v = M[(size_t)b * P1_BLOCKS + t];
        int sc = v;
        #pragma unroll
        for (int off = 1; off < 64; off <<= 1) {
            const int n = __shfl_up(sc, off);
            if (lane >= off) sc += n;
        }
        if (lane == 63) ws[w] = sc;
        __syncthreads();
        int prefix = 0;
        for (int j = 0; j < w; ++j) prefix += ws[j];
        M[(size_t)b * P1_BLOCKS + t] = prefix + sc - v;
        if (t == 255) binCnt[b] = prefix + sc;
        return;
    }
    gemm_body((GA + blockIdx.x - NBINS) * 64,
              x, Bp, xw2, xres, attS, attD, asrc, adst, Alds, logS, logD);
}

// ---------------------------------------------------------------------------
// D3: blocks [0,256) part_mid (lean R10 shape: inline 782-wide binStart scan,
// block 0 publishes binStart, bin-major mid records); [256,+GC) gemm chunk C.
// ---------------------------------------------------------------------------
__global__ __launch_bounds__(256) void k3_part_gemm(
    const float* __restrict__ x, const uint4* __restrict__ Bp,
    uint2* __restrict__ xw2, float* __restrict__ xres,
    const float* __restrict__ attS, const float* __restrict__ attD,
    float* __restrict__ asrc, float* __restrict__ adst,
    const int* __restrict__ ei, const int* __restrict__ M,
    const int* __restrict__ binCnt, int* __restrict__ binStart,
    unsigned* __restrict__ mid)
{
    __shared__ uint4 Alds[4 * NKK * 64];   // 32 KB (aliased by part branch)
    __shared__ float logS[64][HEADS];
    __shared__ float logD[64][HEADS];
    const int t = threadIdx.x, lane = t & 63, wv = t >> 6;

    if (blockIdx.x < P1_BLOCKS) {
        int* bc    = (int*)Alds;           // [782]
        int* bs    = bc + NBINS;           // [782]
        int* baseL = bs + NBINS;           // [782]
        int* lh    = baseL + NBINS;        // [782]
        int* ws    = lh + NBINS;           // [4]
        const int blk = blockIdx.x;

        for (int b = t; b < NBINS; b += 256) {
            bc[b] = binCnt[b];
            baseL[b] = M[(size_t)b * P1_BLOCKS + blk];
            lh[b] = 0;
        }
        __syncthreads();

        int carry = 0;
        for (int c = 0; c < 4; ++c) {
            const int i = (c << 8) + t;
            const int v = (i < NBINS) ? bc[i] : 0;
            int sc = v;
            #pragma unroll
            for (int o = 1; o < 64; o <<= 1) {
                const int n = __shfl_up(sc, o);
                if (lane >= o) sc += n;
            }
            if (lane == 63) ws[wv] = sc;
            __syncthreads();
            int prefix = 0;
            for (int j = 0; j < wv; ++j) prefix += ws[j];
            if (i < NBINS) bs[i] = carry + prefix + sc - v;
            carry += ws[0] + ws[1] + ws[2] + ws[3];
            __syncthreads();   // protect ws before next chunk rewrites it
        }
        for (int b = t; b < NBINS; b += 256) baseL[b] += bs[b];
        if (blk == 0)
            for (int b = t; b < NBINS; b += 256) binStart[b] = bs[b];
        __syncthreads();

        const int e0 = blk * EPB;
        #pragma unroll
        for (int r = 0; r < 13; ++r) {
            const int idx = (r << 8) + t;
            if (idx < EPB) {
                const int e = e0 + idx;
                const int d = ei[N_EDGES + e];
                const int b = d >> 6;
                const int pos = atomicAdd(&lh[b], 1);
                mid[baseL[b] + pos] = ((unsigned)(d & 63) << 17) | (unsigned)ei[e];
            }
        }
        return;
    }
    gemm_body((GA + GB + blockIdx.x - P1_BLOCKS) * 64,
              x, Bp, xw2, xres, attS, attD, asrc, adst, Alds, logS, logD);
}

// ---------------------------------------------------------------------------
// D4: blocks [0,782) scatter_fine2 (lean R10 shape: count + 1-wave 64-scan +
// scatter, derives cnt/lscan from bin structure); [782,+GD) gemm chunk D.
// ---------------------------------------------------------------------------
__global__ __launch_bounds__(256) void k4_scat_gemm(
    const float* __restrict__ x, const uint4* __restrict__ Bp,
    uint2* __restrict__ xw2, float* __restrict__ xres,
    const float* __restrict__ attS, const float* __restrict__ attD,
    float* __restrict__ asrc, float* __restrict__ adst,
    const unsigned* __restrict__ mid, const int* __restrict__ binStart,
    const int* __restrict__ binCnt,
    int* __restrict__ cnt, int* __restrict__ lscan, int* __restrict__ esrc)
{
    __shared__ uint4 Alds[4 * NKK * 64];   // aliased by scatter branch
    __shared__ float logS[64][HEADS];
    __shared__ float logD[64][HEADS];
    const int t = threadIdx.x;

    if (blockIdx.x < NBINS) {
        int*      c64   = (int*)Alds;             // [64]
        int*      o64   = c64 + 64;               // [64]
        unsigned* stash = (unsigned*)(o64 + 64);  // [STASH_CAP]
        const int b = blockIdx.x;

        const int base = binStart[b];
        const int n = binCnt[b];
        if (t < 64) c64[t] = 0;
        __syncthreads();

        for (int i = t; i < n; i += 256) {
            const unsigned m = mid[base + i];
            if (i < STASH_CAP) stash[i] = m;
            atomicAdd(&c64[m >> 17], 1);
        }
        __syncthreads();

        if (t < 64) {                      // single-wave exclusive scan
            const int v = c64[t];
            int sc = v;
            #pragma unroll
            for (int o = 1; o < 64; o <<= 1) {
                const int nn = __shfl_up(sc, o);
                if (t >= o) sc += nn;
            }
            const int ex = sc - v;
            o64[t] = ex;
            const int d = (b << 6) + t;
            if (d < N_NODES) {
                cnt[d] = v;
                lscan[d] = base + ex;
            }
            c64[t] = 0;                    // reuse as running positions
        }
        __syncthreads();

        for (int i = t; i < n; i += 256) {
            const unsigned m = (i < STASH_CAP) ? stash[i] : mid[base + i];
            const int dlo = (int)(m >> 17);
            const int pos = atomicAdd(&c64[dlo], 1);
            esrc[base + o64[dlo] + pos] = (int)(m & 0x1FFFFu);
        }
        return;
    }
    gemm_body((GA + GB + GC + blockIdx.x - NBINS) * 64,
              x, Bp, xw2, xres, attS, attD, asrc, adst, Alds, logS, logD);
}

// ---------------------------------------------------------------------------
// aggregate (R8-measured 64.7us, structural floor): FETCH 214 MB = 8 XCD x
// ~27 MB compulsory per-XCD L2-fill of xw2 at ~3.5 TB/s = 8 x ~450 GB/s
// fabric ports. Random sources -> per-XCD footprint 50000*(1-e^-2) rows.
// padding/scope/MLP/split experiments all null or negative. Single dispatch.
// ---------------------------------------------------------------------------
__global__ __launch_bounds__(256) void aggregate(
    const int* __restrict__ esrc, const int* __restrict__ lscan,
    const int* __restrict__ cnt,
    const float* __restrict__ asrc, const float* __restrict__ adst,
    const uint2* __restrict__ xw2, const float* __restrict__ xres,
    const float* __restrict__ bias, float* __restrict__ out)
{
    __shared__ float4 wbuf[4][64];
    __shared__ int    sbuf[4][64];
    const int t = threadIdx.x;
    const int lane = t & 63;
    const int wv   = t >> 6;

    const int d = blockIdx.x * 4 + wv;                   // 12500*4 = 50000
    const int row = lscan[d];
    const int deg = cnt[d];
    const float4 ad = *reinterpret_cast<const float4*>(adst + (size_t)d * 4);
    const char* xwB = (const char*)xw2;
    const int laneB = lane << 3;

    float dn0 = 0.f, dn1 = 0.f, dn2 = 0.f, dn3 = 0.f;
    float ac0 = 0.f, ac1 = 0.f, ac2 = 0.f, ac3 = 0.f;

    for (int base = 0; base < deg; base += 64) {
        const int m = min(64, deg - base);
        if (lane < m) {
            const int s = esrc[row + base + lane];
            const float4 as = *reinterpret_cast<const float4*>(asrc + (size_t)s * 4);
            const float e0 = __expf(lrelu(as.x + ad.x));
            const float e1 = __expf(lrelu(as.y + ad.y));
            const float e2 = __expf(lrelu(as.z + ad.z));
            const float e3 = __expf(lrelu(as.w + ad.w));
            dn0 += e0; dn1 += e1; dn2 += e2; dn3 += e3;
            wbuf[wv][lane] = make_float4(e0, e1, e2, e3);
            sbuf[wv][lane] = s << 9;   // *512 B node row
        }
        int j = 0;
        for (; j + 4 <= m; j += 4) {
            uint2 v0 = *(const uint2*)(xwB + sbuf[wv][j]     + laneB);
            uint2 v1 = *(const uint2*)(xwB + sbuf[wv][j + 1] + laneB);
            uint2 v2 = *(const uint2*)(xwB + sbuf[wv][j + 2] + laneB);
            uint2 v3 = *(const uint2*)(xwB + sbuf[wv][j + 3] + laneB);
            {
                const float4 w = wbuf[wv][j];
                ac0 = fmaf(w.x, bflo(v0.x), ac0); ac1 = fmaf(w.y, bfhi(v0.x), ac1);
                ac2 = fmaf(w.z, bflo(v0.y), ac2); ac3 = fmaf(w.w, bfhi(v0.y), ac3);
            }
            {
                const float4 w = wbuf[wv][j + 1];
                ac0 = fmaf(w.x, bflo(v1.x), ac0); ac1 = fmaf(w.y, bfhi(v1.x), ac1);
                ac2 = fmaf(w.z, bflo(v1.y), ac2); ac3 = fmaf(w.w, bfhi(v1.y), ac3);
            }
            {
                const float4 w = wbuf[wv][j + 2];
                ac0 = fmaf(w.x, bflo(v2.x), ac0); ac1 = fmaf(w.y, bfhi(v2.x), ac1);
                ac2 = fmaf(w.z, bflo(v2.y), ac2); ac3 = fmaf(w.w, bfhi(v2.y), ac3);
            }
            {
                const float4 w = wbuf[wv][j + 3];
                ac0 = fmaf(w.x, bflo(v3.x), ac0); ac1 = fmaf(w.y, bfhi(v3.x), ac1);
                ac2 = fmaf(w.z, bflo(v3.y), ac2); ac3 = fmaf(w.w, bfhi(v3.y), ac3);
            }
        }
        for (; j < m; ++j) {
            const float4 w = wbuf[wv][j];
            const uint2 v = *(const uint2*)(xwB + sbuf[wv][j] + laneB);
            ac0 = fmaf(w.x, bflo(v.x), ac0);
            ac1 = fmaf(w.y, bfhi(v.x), ac1);
            ac2 = fmaf(w.z, bflo(v.y), ac2);
            ac3 = fmaf(w.w, bfhi(v.y), ac3);
        }
    }

    #pragma unroll
    for (int off = 32; off >= 1; off >>= 1) {
        dn0 += __shfl_xor(dn0, off);
        dn1 += __shfl_xor(dn1, off);
        dn2 += __shfl_xor(dn2, off);
        dn3 += __shfl_xor(dn3, off);
    }
    // self-loop
    const float4 asd = *reinterpret_cast<const float4*>(asrc + (size_t)d * 4);
    const float s0 = __expf(lrelu(asd.x + ad.x));
    const float s1 = __expf(lrelu(asd.y + ad.y));
    const float s2 = __expf(lrelu(asd.z + ad.z));
    const float s3 = __expf(lrelu(asd.w + ad.w));
    const uint2 u = xw2[(size_t)d * 64 + lane];
    ac0 = fmaf(s0, bflo(u.x), ac0); ac1 = fmaf(s1, bfhi(u.x), ac1);
    ac2 = fmaf(s2, bflo(u.y), ac2); ac3 = fmaf(s3, bfhi(u.y), ac3);
    const float i0 = 0.25f / (dn0 + s0);
    const float i1 = 0.25f / (dn1 + s1);
    const float i2 = 0.25f / (dn2 + s2);
    const float i3 = 0.25f / (dn3 + s3);
    const float v = ac0 * i0 + ac1 * i1 + ac2 * i2 + ac3 * i3
                  + bias[lane] + xres[(size_t)d * OUT_CH + lane];
    out[(size_t)d * OUT_CH + lane] = fmaxf(v, 0.f);
}

extern "C" void kernel_launch(void* const* d_in, const int* in_sizes, int n_in,
                              void* d_out, int out_size, void* d_ws, size_t ws_size,
                              hipStream_t stream) {
    const float* x    = (const float*)d_in[0];
    const int*   ei   = (const int*)d_in[1];
    const float* W    = (const float*)d_in[2];
    const float* attS = (const float*)d_in[3];
    const float* attD = (const float*)d_in[4];
    const float* bias = (const float*)d_in[5];
    const float* Wres = (const float*)d_in[6];
    float* out = (float*)d_out;

    char* p = (char*)d_ws;
    uint4*    Bp      = (uint4*)p;    p += (size_t)NKK * NTILES * 64 * 16;  // 160 KB
    uint2*    xw2     = (uint2*)p;    p += (size_t)N_NODES * 64 * 8;        // 25.6 MB
    float*    xres    = (float*)p;    p += (size_t)N_NODES * OUT_CH * 4;    // 12.8 MB
    float*    asrc    = (float*)p;    p += (size_t)N_NODES * HEADS * 4;
    float*    adst    = (float*)p;    p += (size_t)N_NODES * HEADS * 4;
    int*      M       = (int*)p;      p += (size_t)NBINS * P1_BLOCKS * 4;   // 800 KB
    int*      binCnt  = (int*)p;      p += 1024 * 4;
    int*      binStart= (int*)p;      p += 1024 * 4;
    int*      cnt     = (int*)p;      p += (size_t)N_NODES * 4;
    int*      lscan   = (int*)p;      p += (size_t)N_NODES * 4;
    unsigned* mid     = (unsigned*)p; p += (size_t)N_EDGES * 4;             // 3.2 MB
    int*      esrc    = (int*)p;      p += (size_t)N_EDGES * 4;             // 3.2 MB

    pack_B<<<PACK_BLOCKS, 256, 0, stream>>>(W, Wres, Bp);
    k1_hist_gemm<<<P1_BLOCKS + GA, 256, 0, stream>>>(
        x, Bp, xw2, xres, ei, M, attS, attD, asrc, adst);
    k2_scan_gemm<<<NBINS + GB, 256, 0, stream>>>(
        x, Bp, xw2, xres, attS, attD, asrc, adst, M, binCnt);
    k3_part_gemm<<<P1_BLOCKS + GC, 256, 0, stream>>>(
        x, Bp, xw2, xres, attS, attD, asrc, adst, ei, M, binCnt, binStart, mid);
    k4_scat_gemm<<<NBINS + GD, 256, 0, stream>>>(
        x, Bp, xw2, xres, attS, attD, asrc, adst, mid, binStart, binCnt,
        cnt, lscan, esrc);
    aggregate<<<AGG_BLOCKS, 256, 0, stream>>>(
        esrc, lscan, cnt, asrc, adst, xw2, xres, bias, out);
}

// Round 12
// 224.059 us; speedup vs baseline: 1.4629x; 1.4629x over previous
//
#include <hip/hip_runtime.h>
#include <math.h>

#define N_NODES 50000
#define N_EDGES 800000
#define IN_CH   256
#define OUT_CH  64
#define HEADS   4
#define NEG_SLOPE 0.2f
#define NCOLS   320           // W (256) || W_res (64)
#define NTILES  20            // NCOLS / 16
#define NKK     8             // IN_CH / 32
#define PACK_BLOCKS 40        // NKK*NTILES*64 / 256
#define GEMM_BLOCKS 782       // (N_NODES+63)/64
#define NBINS   782           // 64-dst bins (bin = dst>>6); 782*64 = 50048
#define P1_BLOCKS 256         // edge-partition blocks
#define EPB     3125          // edges per partition block = N_EDGES/256
#define AGG_BLOCKS 12500      // N_NODES/4, single dispatch (R8: 64.7us)
#define STASH_CAP 1280        // max edges per 64-dst bin (mean 1023, sd 32)
// R12 schedule law (R11 lesson): the gemm costs ~60-65us PER DISPATCH
// regardless of chunk size (100..782 blocks measured identical) -> never
// chunk it; fuse it with exactly ONE stage, and pick the MOST EXPENSIVE
// stage (part_mid) to hide, not the cheapest (R10 hid hist).

typedef __attribute__((ext_vector_type(8))) short short8;
typedef __attribute__((ext_vector_type(4))) float f32x4;

__device__ __forceinline__ float lrelu(float v) {
    return v > 0.f ? v : NEG_SLOPE * v;
}
__device__ __forceinline__ unsigned bf16_rne(float f) {
    unsigned u = __float_as_uint(f);
    return (u + 0x7FFFu + ((u >> 16) & 1u)) >> 16;
}
__device__ __forceinline__ unsigned pack2(float lo, float hi) {
    return bf16_rne(lo) | (bf16_rne(hi) << 16);
}
__device__ __forceinline__ float bflo(unsigned u) { return __uint_as_float(u << 16); }
__device__ __forceinline__ float bfhi(unsigned u) { return __uint_as_float(u & 0xFFFF0000u); }
__device__ __forceinline__ short8 as_short8(uint4 u) {
    union { uint4 u4; short8 s8; } cv; cv.u4 = u; return cv.s8;
}

// ---------------------------------------------------------------------------
// D1 prep: fused independent halves.
//   blocks [0, P1_BLOCKS)        : histogram (lean R10 shape, own small LDS)
//   blocks [P1_BLOCKS,+PACK)     : pack_B
// ---------------------------------------------------------------------------
__global__ __launch_bounds__(256) void prep(
    const int* __restrict__ ei, int* __restrict__ M,
    const float* __restrict__ W, const float* __restrict__ Wres,
    uint4* __restrict__ Bp)
{
    __shared__ int lh[NBINS];          // 3.1 KB (hist branch only)
    const int t = threadIdx.x;

    if (blockIdx.x < P1_BLOCKS) {
        const int blk = blockIdx.x;
        for (int b = t; b < NBINS; b += 256) lh[b] = 0;
        __syncthreads();
        const int e0 = blk * EPB;
        #pragma unroll
        for (int r = 0; r < 13; ++r) {
            const int idx = (r << 8) + t;
            if (idx < EPB)
                atomicAdd(&lh[ei[N_EDGES + e0 + idx] >> 6], 1);
        }
        __syncthreads();
        for (int b = t; b < NBINS; b += 256)
            M[(size_t)b * P1_BLOCKS + blk] = lh[b];
        return;
    }

    const int idx  = (blockIdx.x - P1_BLOCKS) * 256 + t;   // 0..10239
    const int kk   = idx / (NTILES * 64);
    const int rem  = idx - kk * (NTILES * 64);
    const int tt   = rem >> 6;
    const int lane = rem & 63;
    const int colL = lane & 15, quad = lane >> 4;
    const int col  = tt * 16 + colL;
    const int k0   = kk * 32 + quad * 8;
    float v[8];
    #pragma unroll
    for (int j = 0; j < 8; ++j) {
        const int k = k0 + j;
        v[j] = (col < IN_CH) ? W[(size_t)k * IN_CH + col]
                             : Wres[(size_t)k * OUT_CH + (col - IN_CH)];
    }
    uint4 u;
    u.x = pack2(v[0], v[1]); u.y = pack2(v[2], v[3]);
    u.z = pack2(v[4], v[5]); u.w = pack2(v[6], v[7]);
    Bp[(kk * NTILES + tt) * 64 + lane] = u;
}

// ---------------------------------------------------------------------------
// D2 binscan_M: one block per bin; exclusive-scan M[b][0..255] in place,
// total -> binCnt[b]. 782 blocks. (byte-identical to R10)
// ---------------------------------------------------------------------------
__global__ __launch_bounds__(256) void binscan_M(
    int* __restrict__ M, int* __restrict__ binCnt)
{
    __shared__ int ws[4];
    const int t = threadIdx.x, lane = t & 63, w = t >> 6;
    const int b = blockIdx.x;
    const int v = M[(size_t)b * P1_BLOCKS + t];
    int sc = v;
    #pragma unroll
    for (int off = 1; off < 64; off <<= 1) {
        const int n = __shfl_up(sc, off);
        if (lane >= off) sc += n;
    }
    if (lane == 63) ws[w] = sc;
    __syncthreads();
    int prefix = 0;
    for (int j = 0; j < w; ++j) prefix += ws[j];
    M[(size_t)b * P1_BLOCKS + t] = prefix + sc - v;
    if (t == 255) binCnt[b] = prefix + sc;
}

// ---------------------------------------------------------------------------
// gemm_body: R6/R10's proven 64-row/256-thr MFMA transform + fused logits.
// Wave wv owns col-tiles {wv,4+wv,8+wv,12+wv,16+wv} over 4 row-groups.
// ---------------------------------------------------------------------------
__device__ __forceinline__ void gemm_body(
    const int n0, const float* __restrict__ x, const uint4* __restrict__ Bp,
    uint2* __restrict__ xw2, float* __restrict__ xres,
    const float* __restrict__ attS, const float* __restrict__ attD,
    float* __restrict__ asrc, float* __restrict__ adst,
    uint4* Alds, float (*logS)[HEADS], float (*logD)[HEADS])
{
    const int tid = threadIdx.x;

    logS[tid >> 2][tid & 3] = 0.f;
    logD[tid >> 2][tid & 3] = 0.f;

    #pragma unroll
    for (int i = 0; i < 8; ++i) {
        const int e    = i * 256 + tid;
        const int g    = e >> 9;
        const int kk   = (e >> 6) & 7;
        const int lane = e & 63;
        const int cL   = lane & 15, qd = lane >> 4;
        const int row  = n0 + g * 16 + cL;
        const int k0   = kk * 32 + qd * 8;
        uint4 u = make_uint4(0u, 0u, 0u, 0u);
        if (row < N_NODES) {
            const float4 a = *reinterpret_cast<const float4*>(x + (size_t)row * IN_CH + k0);
            const float4 b = *reinterpret_cast<const float4*>(x + (size_t)row * IN_CH + k0 + 4);
            u.x = pack2(a.x, a.y); u.y = pack2(a.z, a.w);
            u.z = pack2(b.x, b.y); u.w = pack2(b.z, b.w);
        }
        Alds[(g * NKK + kk) * 64 + lane] = u;
    }
    __syncthreads();

    const int lane = tid & 63;
    const int wv   = tid >> 6;
    const int colL = lane & 15, quad = lane >> 4;

    f32x4 acc[4][5];
    #pragma unroll
    for (int rg = 0; rg < 4; ++rg)
        #pragma unroll
        for (int j = 0; j < 5; ++j) acc[rg][j] = (f32x4){0.f, 0.f, 0.f, 0.f};

    for (int kk = 0; kk < NKK; ++kk) {
        uint4 bu[5];
        #pragma unroll
        for (int j = 0; j < 5; ++j)
            bu[j] = Bp[(kk * NTILES + j * 4 + wv) * 64 + lane];
        #pragma unroll
        for (int rg = 0; rg < 4; ++rg) {
            const short8 a = as_short8(Alds[(rg * NKK + kk) * 64 + lane]);
            #pragma unroll
            for (int j = 0; j < 5; ++j)
                acc[rg][j] = __builtin_amdgcn_mfma_f32_16x16x32_bf16(
                    a, as_short8(bu[j]), acc[rg][j], 0, 0, 0);
        }
    }

    #pragma unroll
    for (int rg = 0; rg < 4; ++rg) {
        #pragma unroll
        for (int r = 0; r < 4; ++r) {
            const int row = n0 + rg * 16 + quad * 4 + r;
            if (row < N_NODES) {
                xw2[(size_t)row * 64 + wv * 16 + colL] = make_uint2(
                    pack2(acc[rg][0][r], acc[rg][1][r]),
                    pack2(acc[rg][2][r], acc[rg][3][r]));
                xres[(size_t)row * OUT_CH + wv * 16 + colL] = acc[rg][4][r];
            }
        }
    }

    float aSr[HEADS], aDr[HEADS];
    #pragma unroll
    for (int h = 0; h < HEADS; ++h) {
        aSr[h] = attS[h * 64 + wv * 16 + colL];
        aDr[h] = attD[h * 64 + wv * 16 + colL];
    }
    #pragma unroll
    for (int rg = 0; rg < 4; ++rg) {
        #pragma unroll
        for (int h = 0; h < HEADS; ++h) {
            #pragma unroll
            for (int r = 0; r < 4; ++r) {
                float vS = acc[rg][h][r] * aSr[h];
                float vD = acc[rg][h][r] * aDr[h];
                #pragma unroll
                for (int m = 1; m < 16; m <<= 1) {      // stays within quad
                    vS += __shfl_xor(vS, m);
                    vD += __shfl_xor(vD, m);
                }
                if (colL == 0) {
                    atomicAdd(&logS[rg * 16 + quad * 4 + r][h], vS);
                    atomicAdd(&logD[rg * 16 + quad * 4 + r][h], vD);
                }
            }
        }
    }
    __syncthreads();
    {
        const int rl = tid >> 2, h = tid & 3;
        const int row = n0 + rl;
        if (row < N_NODES) {
            asrc[(size_t)row * HEADS + h] = logS[rl][h];
            adst[(size_t)row * HEADS + h] = logD[rl][h];
        }
    }
}

// ---------------------------------------------------------------------------
// D3 gemm_part: fused — blocks [0,256) part_mid (lean R10 body: inline
// 782-wide binStart scan from binCnt, block 0 publishes binStart, bin-major
// mid records, no global atomics); blocks [256,+782) the FULL gemm.
// part (the most expensive exposed stage, ~40us) hides under the gemm's
// fixed ~65us (R0-R6/R10: fused idle-pipe halves run at max(), not sum()).
// ---------------------------------------------------------------------------
__global__ __launch_bounds__(256) void gemm_part(
    const float* __restrict__ x, const uint4* __restrict__ Bp,
    uint2* __restrict__ xw2, float* __restrict__ xres,
    const float* __restrict__ attS, const float* __restrict__ attD,
    float* __restrict__ asrc, float* __restrict__ adst,
    const int* __restrict__ ei, const int* __restrict__ M,
    const int* __restrict__ binCnt, int* __restrict__ binStart,
    unsigned* __restrict__ mid)
{
    __shared__ uint4 Alds[4 * NKK * 64];   // 32 KB (aliased by part branch)
    __shared__ float logS[64][HEADS];
    __shared__ float logD[64][HEADS];
    const int t = threadIdx.x, lane = t & 63, wv = t >> 6;

    if (blockIdx.x < P1_BLOCKS) {
        int* bc    = (int*)Alds;           // [782]
        int* bs    = bc + NBINS;           // [782]
        int* baseL = bs + NBINS;           // [782]
        int* lh    = baseL + NBINS;        // [782]
        int* ws    = lh + NBINS;           // [4]
        const int blk = blockIdx.x;

        for (int b = t; b < NBINS; b += 256) {
            bc[b] = binCnt[b];
            baseL[b] = M[(size_t)b * P1_BLOCKS + blk];
            lh[b] = 0;
        }
        __syncthreads();

        int carry = 0;
        for (int c = 0; c < 4; ++c) {
            const int i = (c << 8) + t;
            const int v = (i < NBINS) ? bc[i] : 0;
            int sc = v;
            #pragma unroll
            for (int o = 1; o < 64; o <<= 1) {
                const int n = __shfl_up(sc, o);
                if (lane >= o) sc += n;
            }
            if (lane == 63) ws[wv] = sc;
            __syncthreads();
            int prefix = 0;
            for (int j = 0; j < wv; ++j) prefix += ws[j];
            if (i < NBINS) bs[i] = carry + prefix + sc - v;
            carry += ws[0] + ws[1] + ws[2] + ws[3];
            __syncthreads();   // protect ws before next chunk rewrites it
        }
        for (int b = t; b < NBINS; b += 256) baseL[b] += bs[b];
        if (blk == 0)
            for (int b = t; b < NBINS; b += 256) binStart[b] = bs[b];
        __syncthreads();

        const int e0 = blk * EPB;
        #pragma unroll
        for (int r = 0; r < 13; ++r) {
            const int idx = (r << 8) + t;
            if (idx < EPB) {
                const int e = e0 + idx;
                const int d = ei[N_EDGES + e];
                const int b = d >> 6;
                const int pos = atomicAdd(&lh[b], 1);
                mid[baseL[b] + pos] = ((unsigned)(d & 63) << 17) | (unsigned)ei[e];
            }
        }
        return;
    }
    gemm_body((blockIdx.x - P1_BLOCKS) * 64,
              x, Bp, xw2, xres, attS, attD, asrc, adst, Alds, logS, logD);
}

// ---------------------------------------------------------------------------
// D4 scatter_fine2 (byte-identical to R10): one block per 64-dst bin, 782
// blocks. Count + single-wave 64-scan + scatter; derives global CSR offsets
// lscan[d] = binStart[b] + within-bin prefix. Writes cnt/lscan/esrc.
// ---------------------------------------------------------------------------
__global__ __launch_bounds__(256) void scatter_fine2(
    const unsigned* __restrict__ mid, const int* __restrict__ binStart,
    const int* __restrict__ binCnt,
    int* __restrict__ cnt, int* __restrict__ lscan, int* __restrict__ esrc)
{
    __shared__ int c64[64];
    __shared__ int o64[64];
    __shared__ unsigned stash[STASH_CAP];
    const int t = threadIdx.x;
    const int b = blockIdx.x;

    const int base = binStart[b];
    const int n = binCnt[b];
    if (t < 64) c64[t] = 0;
    __syncthreads();

    for (int i = t; i < n; i += 256) {
        const unsigned m = mid[base + i];
        if (i < STASH_CAP) stash[i] = m;
        atomicAdd(&c64[m >> 17], 1);
    }
    __syncthreads();

    if (t < 64) {                      // single-wave exclusive scan
        const int v = c64[t];
        int sc = v;
        #pragma unroll
        for (int o = 1; o < 64; o <<= 1) {
            const int nn = __shfl_up(sc, o);
            if (t >= o) sc += nn;
        }
        const int ex = sc - v;
        o64[t] = ex;
        const int d = (b << 6) + t;
        if (d < N_NODES) {
            cnt[d] = v;
            lscan[d] = base + ex;
        }
        c64[t] = 0;                    // reuse as running positions
    }
    __syncthreads();

    for (int i = t; i < n; i += 256) {
        const unsigned m = (i < STASH_CAP) ? stash[i] : mid[base + i];
        const int dlo = (int)(m >> 17);
        const int pos = atomicAdd(&c64[dlo], 1);
        esrc[base + o64[dlo] + pos] = (int)(m & 0x1FFFFu);
    }
}

// ---------------------------------------------------------------------------
// D5 aggregate (byte-identical to R8/R10, measured 64.7us structural floor):
// FETCH 214 MB = 8 XCD x ~27 MB compulsory per-XCD L2-fill of xw2 at
// ~3.5 TB/s = 8 x ~450 GB/s fabric ports. Random sources -> per-XCD
// footprint 50000*(1-e^-2) rows. All MLP/scope/padding/split probes null.
// ---------------------------------------------------------------------------
__global__ __launch_bounds__(256) void aggregate(
    const int* __restrict__ esrc, const int* __restrict__ lscan,
    const int* __restrict__ cnt,
    const float* __restrict__ asrc, const float* __restrict__ adst,
    const uint2* __restrict__ xw2, const float* __restrict__ xres,
    const float* __restrict__ bias, float* __restrict__ out)
{
    __shared__ float4 wbuf[4][64];
    __shared__ int    sbuf[4][64];
    const int t = threadIdx.x;
    const int lane = t & 63;
    const int wv   = t >> 6;

    const int d = blockIdx.x * 4 + wv;                   // 12500*4 = 50000
    const int row = lscan[d];
    const int deg = cnt[d];
    const float4 ad = *reinterpret_cast<const float4*>(adst + (size_t)d * 4);
    const char* xwB = (const char*)xw2;
    const int laneB = lane << 3;

    float dn0 = 0.f, dn1 = 0.f, dn2 = 0.f, dn3 = 0.f;
    float ac0 = 0.f, ac1 = 0.f, ac2 = 0.f, ac3 = 0.f;

    for (int base = 0; base < deg; base += 64) {
        const int m = min(64, deg - base);
        if (lane < m) {
            const int s = esrc[row + base + lane];
            const float4 as = *reinterpret_cast<const float4*>(asrc + (size_t)s * 4);
            const float e0 = __expf(lrelu(as.x + ad.x));
            const float e1 = __expf(lrelu(as.y + ad.y));
            const float e2 = __expf(lrelu(as.z + ad.z));
            const float e3 = __expf(lrelu(as.w + ad.w));
            dn0 += e0; dn1 += e1; dn2 += e2; dn3 += e3;
            wbuf[wv][lane] = make_float4(e0, e1, e2, e3);
            sbuf[wv][lane] = s << 9;   // *512 B node row
        }
        int j = 0;
        for (; j + 4 <= m; j += 4) {
            uint2 v0 = *(const uint2*)(xwB + sbuf[wv][j]     + laneB);
            uint2 v1 = *(const uint2*)(xwB + sbuf[wv][j + 1] + laneB);
            uint2 v2 = *(const uint2*)(xwB + sbuf[wv][j + 2] + laneB);
            uint2 v3 = *(const uint2*)(xwB + sbuf[wv][j + 3] + laneB);
            {
                const float4 w = wbuf[wv][j];
                ac0 = fmaf(w.x, bflo(v0.x), ac0); ac1 = fmaf(w.y, bfhi(v0.x), ac1);
                ac2 = fmaf(w.z, bflo(v0.y), ac2); ac3 = fmaf(w.w, bfhi(v0.y), ac3);
            }
            {
                const float4 w = wbuf[wv][j + 1];
                ac0 = fmaf(w.x, bflo(v1.x), ac0); ac1 = fmaf(w.y, bfhi(v1.x), ac1);
                ac2 = fmaf(w.z, bflo(v1.y), ac2); ac3 = fmaf(w.w, bfhi(v1.y), ac3);
            }
            {
                const float4 w = wbuf[wv][j + 2];
                ac0 = fmaf(w.x, bflo(v2.x), ac0); ac1 = fmaf(w.y, bfhi(v2.x), ac1);
                ac2 = fmaf(w.z, bflo(v2.y), ac2); ac3 = fmaf(w.w, bfhi(v2.y), ac3);
            }
            {
                const float4 w = wbuf[wv][j + 3];
                ac0 = fmaf(w.x, bflo(v3.x), ac0); ac1 = fmaf(w.y, bfhi(v3.x), ac1);
                ac2 = fmaf(w.z, bflo(v3.y), ac2); ac3 = fmaf(w.w, bfhi(v3.y), ac3);
            }
        }
        for (; j < m; ++j) {
            const float4 w = wbuf[wv][j];
            const uint2 v = *(const uint2*)(xwB + sbuf[wv][j] + laneB);
            ac0 = fmaf(w.x, bflo(v.x), ac0);
            ac1 = fmaf(w.y, bfhi(v.x), ac1);
            ac2 = fmaf(w.z, bflo(v.y), ac2);
            ac3 = fmaf(w.w, bfhi(v.y), ac3);
        }
    }

    #pragma unroll
    for (int off = 32; off >= 1; off >>= 1) {
        dn0 += __shfl_xor(dn0, off);
        dn1 += __shfl_xor(dn1, off);
        dn2 += __shfl_xor(dn2, off);
        dn3 += __shfl_xor(dn3, off);
    }
    // self-loop
    const float4 asd = *reinterpret_cast<const float4*>(asrc + (size_t)d * 4);
    const float s0 = __expf(lrelu(asd.x + ad.x));
    const float s1 = __expf(lrelu(asd.y + ad.y));
    const float s2 = __expf(lrelu(asd.z + ad.z));
    const float s3 = __expf(lrelu(asd.w + ad.w));
    const uint2 u = xw2[(size_t)d * 64 + lane];
    ac0 = fmaf(s0, bflo(u.x), ac0); ac1 = fmaf(s1, bfhi(u.x), ac1);
    ac2 = fmaf(s2, bflo(u.y), ac2); ac3 = fmaf(s3, bfhi(u.y), ac3);
    const float i0 = 0.25f / (dn0 + s0);
    const float i1 = 0.25f / (dn1 + s1);
    const float i2 = 0.25f / (dn2 + s2);
    const float i3 = 0.25f / (dn3 + s3);
    const float v = ac0 * i0 + ac1 * i1 + ac2 * i2 + ac3 * i3
                  + bias[lane] + xres[(size_t)d * OUT_CH + lane];
    out[(size_t)d * OUT_CH + lane] = fmaxf(v, 0.f);
}

extern "C" void kernel_launch(void* const* d_in, const int* in_sizes, int n_in,
                              void* d_out, int out_size, void* d_ws, size_t ws_size,
                              hipStream_t stream) {
    const float* x    = (const float*)d_in[0];
    const int*   ei   = (const int*)d_in[1];
    const float* W    = (const float*)d_in[2];
    const float* attS = (const float*)d_in[3];
    const float* attD = (const float*)d_in[4];
    const float* bias = (const float*)d_in[5];
    const float* Wres = (const float*)d_in[6];
    float* out = (float*)d_out;

    char* p = (char*)d_ws;
    uint4*    Bp      = (uint4*)p;    p += (size_t)NKK * NTILES * 64 * 16;  // 160 KB
    uint2*    xw2     = (uint2*)p;    p += (size_t)N_NODES * 64 * 8;        // 25.6 MB
    float*    xres    = (float*)p;    p += (size_t)N_NODES * OUT_CH * 4;    // 12.8 MB
    float*    asrc    = (float*)p;    p += (size_t)N_NODES * HEADS * 4;
    float*    adst    = (float*)p;    p += (size_t)N_NODES * HEADS * 4;
    int*      M       = (int*)p;      p += (size_t)NBINS * P1_BLOCKS * 4;   // 800 KB
    int*      binCnt  = (int*)p;      p += 1024 * 4;
    int*      binStart= (int*)p;      p += 1024 * 4;
    int*      cnt     = (int*)p;      p += (size_t)N_NODES * 4;
    int*      lscan   = (int*)p;      p += (size_t)N_NODES * 4;
    unsigned* mid     = (unsigned*)p; p += (size_t)N_EDGES * 4;             // 3.2 MB
    int*      esrc    = (int*)p;      p += (size_t)N_EDGES * 4;             // 3.2 MB

    prep<<<P1_BLOCKS + PACK_BLOCKS, 256, 0, stream>>>(ei, M, W, Wres, Bp);
    binscan_M<<<NBINS, 256, 0, stream>>>(M, binCnt);
    gemm_part<<<P1_BLOCKS + GEMM_BLOCKS, 256, 0, stream>>>(
        x, Bp, xw2, xres, attS, attD, asrc, adst, ei, M, binCnt, binStart, mid);
    scatter_fine2<<<NBINS, 256, 0, stream>>>(
        mid, binStart, binCnt, cnt, lscan, esrc);
    aggregate<<<AGG_BLOCKS, 256, 0, stream>>>(
        esrc, lscan, cnt, asrc, adst, xw2, xres, bias, out);
}